// Round 2
// baseline (1047.226 us; speedup 1.0000x reference)
//
#include <hip/hip_runtime.h>
#include <stdint.h>

// ---------------------------------------------------------------------------
// FullTensorProduct: out[n,c] = sum_{a,b} x1[n,a] x2[n,b] w3j[a,b,c]
// LMAX1=LMAX2=3 -> x1,x2: [N,16], out: [N,170].
// w3j rebuilt on-device every launch (ws is re-poisoned; graph-capture-safe).
// Input/output dtype (f32 vs bf16) detected at runtime from bit patterns:
// branch is uniform and data is identical every call.
// ---------------------------------------------------------------------------

#define KSTR 52   // per-c entry stride in sparse table (max real count 49)

struct PathT { int l1, l2, l3, so; };

// Paths sorted stably by lout (replicates np.lexsort in build_w3j); so = output
// offset of each (l1,l2,lout) block within the 170-dim output.
__constant__ PathT g_paths[30] = {
    {0,0,0,0},{1,1,0,1},{2,2,0,2},{3,3,0,3},
    {0,1,1,4},{1,0,1,7},{1,2,1,10},{2,1,1,13},{2,3,1,16},{3,2,1,19},
    {0,2,2,22},{1,1,2,27},{1,3,2,32},{2,0,2,37},{2,2,2,42},{3,1,2,47},{3,3,2,52},
    {0,3,3,57},{1,2,3,64},{2,1,3,71},{2,3,3,78},{3,0,3,85},{3,2,3,92},
    {1,3,4,99},{2,2,4,108},{3,1,4,117},{3,3,4,126},
    {2,3,5,135},{3,2,5,146},
    {3,3,6,157}
};

__constant__ double g_fact[14] = {
    1.0, 1.0, 2.0, 6.0, 24.0, 120.0, 720.0, 5040.0, 40320.0, 362880.0,
    3628800.0, 39916800.0, 479001600.0, 6227020800.0
};

struct cd { double re, im; };

__device__ __forceinline__ cd cmul(cd a, cd b) {
    return { a.re*b.re - a.im*b.im, a.re*b.im + a.im*b.re };
}

// <j1 m1 j2 m2 | j3 m3>, Racah formula. Factorial args <= 13, exact in double.
__device__ double cg_su2(int j1, int m1, int j2, int m2, int j3, int m3) {
    if (m3 != m1 + m2) return 0.0;
    double pref = sqrt((double)(2*j3+1) * g_fact[j3+j1-j2] * g_fact[j3-j1+j2]
                       * g_fact[j1+j2-j3] / g_fact[j1+j2+j3+1]);
    pref *= sqrt(g_fact[j3+m3]*g_fact[j3-m3]*g_fact[j1-m1]*g_fact[j1+m1]
                 *g_fact[j2-m2]*g_fact[j2+m2]);
    double s = 0.0;
    for (int k = 0; k <= j1+j2-j3; ++k) {
        int a = j1-m1-k, b = j2+m2-k, c = j3-j2+m1+k, d = j3-j1-m2+k;
        if (a < 0 || b < 0 || c < 0 || d < 0) continue;
        double t = 1.0 / (g_fact[k]*g_fact[j1+j2-j3-k]*g_fact[a]*g_fact[b]
                          *g_fact[c]*g_fact[d]);
        s += (k & 1) ? -t : t;
    }
    return pref * s;
}

// Entry (row,col) of real->complex change-of-basis matrix for degree l,
// including the (-i)^l phase. row = l + m_complex, col = real index.
__device__ cd qent(int l, int row, int col) {
    const double is2 = 0.70710678118654752440;
    int m = row - l;
    cd q = {0.0, 0.0};
    if (m < 0) {
        if (col == l - m)      q = { is2, 0.0 };
        else if (col == l + m) q = { 0.0, -is2 };
    } else if (m == 0) {
        if (col == l)          q = { 1.0, 0.0 };
    } else {
        double sgn = (m & 1) ? -1.0 : 1.0;
        if (col == l + m)      q = { sgn*is2, 0.0 };
        else if (col == l - m) q = { 0.0, sgn*is2 };
    }
    switch (l & 3) {                       // multiply by (-i)^l
        case 1: q = {  q.im, -q.re }; break;
        case 2: q = { -q.re, -q.im }; break;
        case 3: q = { -q.im,  q.re }; break;
        default: break;
    }
    return q;
}

// Detect input dtype: bf16 buffers have ~100% plausible bf16 exponent fields;
// f32 buffers read as u16 have ~62% (low mantissa halves are uniform bits).
__global__ void detect_dtype_kernel(const unsigned short* __restrict__ x,
                                    int n_u16_min, int* __restrict__ flag) {
    __shared__ int s[256];
    const int tid = threadIdx.x;
    int ncheck = n_u16_min < 8192 ? n_u16_min : 8192;
    int good = 0;
    for (int i = tid; i < ncheck; i += 256) {
        unsigned short v = x[i];
        int e = (v >> 7) & 0xFF;
        good += (v == 0 || (e >= 97 && e <= 158)) ? 1 : 0;
    }
    s[tid] = good;
    __syncthreads();
    for (int t = 128; t > 0; t >>= 1) {
        if (tid < t) s[tid] += s[tid + t];
        __syncthreads();
    }
    if (tid == 0) *flag = (s[0] * 10 >= ncheck * 9) ? 1 : 0;  // 1 = bf16
}

// One block per path: real-basis CG block in fp64, Frobenius-normalized,
// scaled by sqrt(2*lout+1), written into dense w3j[16][16][170].
__global__ void build_w3j_kernel(float* __restrict__ dense) {
    const int p  = blockIdx.x;
    const int l1 = g_paths[p].l1, l2 = g_paths[p].l2, l3 = g_paths[p].l3;
    const int so = g_paths[p].so;
    const int D1 = 2*l1+1, D2 = 2*l2+1, D3 = 2*l3+1;
    const int M  = D1*D2*D3;
    const int tid = threadIdx.x;

    __shared__ double sC[49];
    __shared__ double sCr[640];
    __shared__ double sred[256];

    for (int e = tid; e < D1*D2; e += blockDim.x) {
        int i = e / D2, k = e - i*D2;
        int m1 = i - l1, m2 = k - l2, m3 = m1 + m2;
        int am3 = m3 < 0 ? -m3 : m3;
        sC[e] = (am3 <= l3) ? cg_su2(l1, m1, l2, m2, l3, m3) : 0.0;
    }
    __syncthreads();

    double part = 0.0;
    for (int e = tid; e < M; e += blockDim.x) {
        int j  = e / (D2*D3);
        int r  = e - j*(D2*D3);
        int li = r / D3;
        int n  = r - li*D3;
        cd z = {0.0, 0.0};
        for (int i = 0; i < D1; ++i) {
            for (int k = 0; k < D2; ++k) {
                int m3 = (i - l1) + (k - l2);
                if (m3 < -l3 || m3 > l3) continue;
                double cval = sC[i*D2 + k];
                if (cval == 0.0) continue;
                cd q1 = qent(l1, i, j);
                if (q1.re == 0.0 && q1.im == 0.0) continue;
                cd q2 = qent(l2, k, li);
                if (q2.re == 0.0 && q2.im == 0.0) continue;
                cd q3 = qent(l3, l3 + m3, n);
                q3.im = -q3.im;  // conj
                cd t = cmul(cmul(q1, q2), q3);
                z.re += t.re * cval;
                z.im += t.im * cval;
            }
        }
        sCr[e] = z.re;
        part += z.re * z.re;
    }
    sred[tid] = part;
    __syncthreads();
    for (int s = 128; s > 0; s >>= 1) {
        if (tid < s) sred[tid] += sred[tid + s];
        __syncthreads();
    }
    const double scale = sqrt((double)(2*l3+1)) / sqrt(sred[0]);

    for (int e = tid; e < M; e += blockDim.x) {
        int j  = e / (D2*D3);
        int r  = e - j*(D2*D3);
        int li = r / D3;
        int n  = r - li*D3;
        int a = l1*l1 + j, b = l2*l2 + li, c = so + n;
        dense[(a*16 + b)*170 + c] = (float)(sCr[e] * scale);
    }
}

// Compact dense block into per-c sparse table: entries {a*16+b, value}.
__global__ void build_table_kernel(const float* __restrict__ dense,
                                   int* __restrict__ cnt,
                                   int2* __restrict__ tbl) {
    int c = blockIdx.x * blockDim.x + threadIdx.x;
    if (c >= 170) return;
    int l1 = 0, l2 = 0;
    for (int p = 0; p < 30; ++p) {
        int w = 2*g_paths[p].l3 + 1;
        if (c >= g_paths[p].so && c < g_paths[p].so + w) {
            l1 = g_paths[p].l1; l2 = g_paths[p].l2;
            break;
        }
    }
    int D1 = 2*l1+1, D2 = 2*l2+1;
    int count = 0;
    for (int i = 0; i < D1; ++i) {
        for (int k = 0; k < D2; ++k) {
            int a = l1*l1 + i, b = l2*l2 + k;
            float v = dense[(a*16 + b)*170 + c];
            if (fabsf(v) > 1e-6f) {
                tbl[c*KSTR + count] = make_int2(a*16 + b, __float_as_int(v));
                ++count;
            }
        }
    }
    cnt[c] = count;
}

// Main: one wave per row; lanes cover c in 3 passes of 64 -> coalesced stores.
// Per-row product table prod[ab] = x1[a]*x2[b]; inner loop = 1 LDS read + FMA
// per nonzero. Dtype mode read from device flag (uniform branch).
__global__ __launch_bounds__(256)
void tp_kernel(const void* __restrict__ x1v,
               const void* __restrict__ x2v,
               const int*  __restrict__ cnt,
               const int2* __restrict__ tbl,
               const int*  __restrict__ flag,
               void* __restrict__ outv,
               int nrows) {
    __shared__ float xs[4][32];
    __shared__ float prod[4][256];

    const int w    = threadIdx.x >> 6;
    const int lane = threadIdx.x & 63;
    const int row  = blockIdx.x * 4 + w;
    const int mode = *flag;   // 1 = bf16, 0 = f32 (uniform across grid)

    if (row < nrows && lane < 32) {
        float v;
        if (mode) {
            const unsigned short* p = (lane < 16)
                ? (const unsigned short*)x1v + row*16 + lane
                : (const unsigned short*)x2v + row*16 + lane - 16;
            v = __uint_as_float(((unsigned int)(*p)) << 16);
        } else {
            v = (lane < 16) ? ((const float*)x1v)[row*16 + lane]
                            : ((const float*)x2v)[row*16 + lane - 16];
        }
        xs[w][lane] = v;
    }
    __syncthreads();

    if (row < nrows) {
        #pragma unroll
        for (int q = 0; q < 4; ++q) {
            int idx = q*64 + lane;
            prod[w][idx] = xs[w][idx >> 4] * xs[w][16 + (idx & 15)];
        }
    }
    __syncthreads();
    if (row >= nrows) return;

    #pragma unroll
    for (int p = 0; p < 3; ++p) {
        int c = p*64 + lane;
        if (c < 170) {
            float acc = 0.0f;
            int nc = cnt[c];
            const int2* t = tbl + c*KSTR;
            for (int k = 0; k < nc; ++k) {
                int2 e = t[k];
                acc += __int_as_float(e.y) * prod[w][e.x];
            }
            if (mode) {
                unsigned int xb = __float_as_uint(acc);
                unsigned int r  = (xb + 0x7fffu + ((xb >> 16) & 1u)) >> 16;
                ((unsigned short*)outv)[row*170 + c] = (unsigned short)r;
            } else {
                ((float*)outv)[row*170 + c] = acc;
            }
        }
    }
}

extern "C" void kernel_launch(void* const* d_in, const int* in_sizes, int n_in,
                              void* d_out, int out_size, void* d_ws, size_t ws_size,
                              hipStream_t stream) {
    const void* x1 = d_in[0];
    const void* x2 = d_in[1];

    char* ws = (char*)d_ws;
    float* dense = (float*)ws;               // 16*16*170 f32 = 174080 B
    int*   cnt   = (int*)(ws + 174080);      // 170 ints = 680 B
    int2*  tbl   = (int2*)(ws + 175104);     // 170*KSTR int2 = 70720 B
    int*   flag  = (int*)(ws + 245824);      // 4 B

    int nrows = in_sizes[0] / 16;            // 500000

    detect_dtype_kernel<<<dim3(1), dim3(256), 0, stream>>>(
        (const unsigned short*)x1, in_sizes[0], flag);
    build_w3j_kernel<<<dim3(30), dim3(256), 0, stream>>>(dense);
    build_table_kernel<<<dim3(1), dim3(256), 0, stream>>>(dense, cnt, tbl);

    int nblocks = (nrows + 3) / 4;
    tp_kernel<<<dim3(nblocks), dim3(256), 0, stream>>>(
        x1, x2, cnt, tbl, flag, d_out, nrows);
}